// Round 1
// baseline (10721.404 us; speedup 1.0000x reference)
//
#include <hip/hip_runtime.h>

#define HH 51
#define G4 204          // 4*H
#define ROWPAD 56       // LDS row pad: (14*j) mod 32 hits 16 distinct banks/phase -> conflict-free b128

__device__ __forceinline__ float rl(float v, int k) {
    return __int_as_float(__builtin_amdgcn_readlane(__float_as_int(v), k));
}
__device__ __forceinline__ float sigm(float x) {
    return 1.0f / (1.0f + __expf(-x));
}
__device__ __forceinline__ float tanhf_fast(float x) {
    // tanh(x) = 1 - 2/(exp(2x)+1); saturates correctly for |x| large
    return 1.0f - 2.0f / (__expf(2.0f * x) + 1.0f);
}

__global__ void __launch_bounds__(64, 1)
lstm2_kernel(const float* __restrict__ input,
             const float* __restrict__ w_ih1, const float* __restrict__ w_hh1,
             const float* __restrict__ b_ih1, const float* __restrict__ b_hh1,
             const float* __restrict__ w_ih2, const float* __restrict__ w_hh2,
             const float* __restrict__ b_ih2, const float* __restrict__ b_hh2,
             const float* __restrict__ w_lin, const float* __restrict__ b_lin,
             float* __restrict__ out, int T)
{
    __shared__ float sW2[G4][ROWPAD];   // w_hh2, rows padded to 56 floats (cols >=51 are 0)

    const int lane = threadIdx.x;
    const int b    = blockIdx.x;

    // ---- stage w_hh2 into LDS (one-time) ----
    for (int idx = lane; idx < G4 * ROWPAD; idx += 64) {
        int r = idx / ROWPAD, c = idx % ROWPAD;
        sW2[r][c] = (c < HH) ? w_hh2[r * HH + c] : 0.0f;
    }
    __syncthreads();

    const bool act = lane < HH;
    const int  j   = act ? lane : 0;   // inactive lanes mirror unit 0 (keeps values finite)

    // ---- per-lane scalar weights / fused biases ----
    const float wxi = w_ih1[j],        wxf = w_ih1[HH + j],
                wxg = w_ih1[2*HH + j], wxo = w_ih1[3*HH + j];
    const float bi1 = b_ih1[j]        + b_hh1[j];
    const float bf1 = b_ih1[HH + j]   + b_hh1[HH + j];
    const float bg1 = b_ih1[2*HH + j] + b_hh1[2*HH + j];
    const float bo1 = b_ih1[3*HH + j] + b_hh1[3*HH + j];
    const float bi2 = b_ih2[j]        + b_hh2[j];
    const float bf2 = b_ih2[HH + j]   + b_hh2[HH + j];
    const float bg2 = b_ih2[2*HH + j] + b_hh2[2*HH + j];
    const float bo2 = b_ih2[3*HH + j] + b_hh2[3*HH + j];
    const float wl  = w_lin[j];
    const float bl  = b_lin[0];

    // ---- register-resident weights: w_hh1 rows {j,51+j,102+j,153+j}, same for w_ih2 ----
    float Wh1[4][HH];
    float Wi2[4][HH];
#pragma unroll
    for (int g = 0; g < 4; ++g) {
#pragma unroll
        for (int k = 0; k < HH; ++k) {
            Wh1[g][k] = w_hh1[(g*HH + j)*HH + k];
            Wi2[g][k] = w_ih2[(g*HH + j)*HH + k];
        }
    }

    // LDS row pointers for this lane's w_hh2 gate rows (loop-invariant)
    const float4* pI = (const float4*)sW2[j];
    const float4* pF = (const float4*)sW2[HH + j];
    const float4* pG = (const float4*)sW2[2*HH + j];
    const float4* pO = (const float4*)sW2[3*HH + j];

    // ---- state ----
    float h1 = 0.0f, c1 = 0.0f, h2 = 0.0f, c2 = 0.0f;

    const float* xrow = input + (size_t)b * T;
    float*       orow = out   + (size_t)b * T;

    for (int t0 = 0; t0 < T; t0 += 64) {
        const float xv = xrow[t0 + lane];            // coalesced prefetch of 64 x values

        for (int tt = 0; tt < 64; ++tt) {
            // ================= Phase A: layer2 hh-part (uses OLD h2, LDS weights) ============
            float a2i = bi2, a2f = bf2, a2g = bg2, a2o = bo2;
#pragma unroll
            for (int k4 = 0; k4 < 13; ++k4) {
                const float4 wi = pI[k4], wf = pF[k4], wg = pG[k4], wo = pO[k4];
                const float h0 = rl(h2, 4*k4 + 0);
                const float h1v = rl(h2, 4*k4 + 1);
                const float h2v = rl(h2, 4*k4 + 2);
                const float h3v = rl(h2, 4*k4 + 3);   // k=51 pairs with zero weight pad
                a2i = fmaf(wi.x, h0, a2i); a2i = fmaf(wi.y, h1v, a2i);
                a2i = fmaf(wi.z, h2v, a2i); a2i = fmaf(wi.w, h3v, a2i);
                a2f = fmaf(wf.x, h0, a2f); a2f = fmaf(wf.y, h1v, a2f);
                a2f = fmaf(wf.z, h2v, a2f); a2f = fmaf(wf.w, h3v, a2f);
                a2g = fmaf(wg.x, h0, a2g); a2g = fmaf(wg.y, h1v, a2g);
                a2g = fmaf(wg.z, h2v, a2g); a2g = fmaf(wg.w, h3v, a2g);
                a2o = fmaf(wo.x, h0, a2o); a2o = fmaf(wo.y, h1v, a2o);
                a2o = fmaf(wo.z, h2v, a2o); a2o = fmaf(wo.w, h3v, a2o);
            }

            // ================= Phase B: layer1 (x + w_hh1 @ h1, register weights) ============
            const float x = rl(xv, tt);
            float a1i = fmaf(wxi, x, bi1);
            float a1f = fmaf(wxf, x, bf1);
            float a1g = fmaf(wxg, x, bg1);
            float a1o = fmaf(wxo, x, bo1);
#pragma unroll
            for (int k = 0; k < HH; ++k) {
                const float hk = rl(h1, k);
                a1i = fmaf(Wh1[0][k], hk, a1i);
                a1f = fmaf(Wh1[1][k], hk, a1f);
                a1g = fmaf(Wh1[2][k], hk, a1g);
                a1o = fmaf(Wh1[3][k], hk, a1o);
            }
            const float c1n = sigm(a1f) * c1 + sigm(a1i) * tanhf_fast(a1g);
            const float h1n = sigm(a1o) * tanhf_fast(c1n);
            c1 = c1n; h1 = h1n;

            // ================= Phase C: layer2 ih-part (uses NEW h1, register weights) =======
#pragma unroll
            for (int k = 0; k < HH; ++k) {
                const float hk = rl(h1, k);
                a2i = fmaf(Wi2[0][k], hk, a2i);
                a2f = fmaf(Wi2[1][k], hk, a2f);
                a2g = fmaf(Wi2[2][k], hk, a2g);
                a2o = fmaf(Wi2[3][k], hk, a2o);
            }
            const float c2n = sigm(a2f) * c2 + sigm(a2i) * tanhf_fast(a2g);
            const float h2n = sigm(a2o) * tanhf_fast(c2n);
            c2 = c2n; h2 = h2n;

            // ================= Phase D: y = h2 . w_lin + b_lin, butterfly reduce =============
            float p = act ? h2 * wl : 0.0f;
#pragma unroll
            for (int m = 32; m >= 1; m >>= 1) p += __shfl_xor(p, m, 64);
            if (lane == 0) orow[t0 + tt] = p + bl;
        }
    }
}

extern "C" void kernel_launch(void* const* d_in, const int* in_sizes, int n_in,
                              void* d_out, int out_size, void* d_ws, size_t ws_size,
                              hipStream_t stream) {
    const float* input = (const float*)d_in[0];
    // d_in[1] = future (scalar int, fixed 0 in this problem) -- ignored
    const float* w_ih1 = (const float*)d_in[2];
    const float* w_hh1 = (const float*)d_in[3];
    const float* b_ih1 = (const float*)d_in[4];
    const float* b_hh1 = (const float*)d_in[5];
    const float* w_ih2 = (const float*)d_in[6];
    const float* w_hh2 = (const float*)d_in[7];
    const float* b_ih2 = (const float*)d_in[8];
    const float* b_hh2 = (const float*)d_in[9];
    const float* w_lin = (const float*)d_in[10];
    const float* b_lin = (const float*)d_in[11];
    float* out = (float*)d_out;

    const int T = 1024;
    const int B = in_sizes[0] / T;   // 1024

    lstm2_kernel<<<B, 64, 0, stream>>>(input,
                                       w_ih1, w_hh1, b_ih1, b_hh1,
                                       w_ih2, w_hh2, b_ih2, b_hh2,
                                       w_lin, b_lin, out, T);
}

// Round 2
// 2263.255 us; speedup vs baseline: 4.7372x; 4.7372x over previous
//
#include <hip/hip_runtime.h>
#include <hip/hip_fp16.h>

#define HH 51
#define G4 204
#define RP   72                    // halves per LDS row (pitch 144 B)
#define RPB  144
#define GOFF (51 * RPB)            // 7344 B between gate blocks
#define MOFF1 (G4 * RP * 2)        // 29376 B: offset of second matrix (w_hh2)

typedef unsigned int u32;

__device__ __forceinline__ float rlf(float v, int k) {
    return __int_as_float(__builtin_amdgcn_readlane(__float_as_int(v), k));
}
__device__ __forceinline__ float rcp_fast(float x) {
    float r; asm("v_rcp_f32 %0, %1" : "=v"(r) : "v"(x)); return r;
}
__device__ __forceinline__ float sigm(float x) {
    return rcp_fast(1.0f + __expf(-x));
}
__device__ __forceinline__ float tanh_fast(float x) {
    // tanh(x) = 1 - 2/(exp(2x)+1)
    return fmaf(-2.0f, rcp_fast(__expf(2.0f * x) + 1.0f), 1.0f);
}

// fp16 (lo/hi half of packed u32) * fp32(SGPR) + fp32 accumulator, full fp32 accumulate
#define FMA_LO(acc, pk, hs) asm("v_fma_mix_f32 %0, %1, %2, %0 op_sel:[0,0,0] op_sel_hi:[1,0,0]" : "+v"(acc) : "v"(pk), "s"(hs))
#define FMA_HI(acc, pk, hs) asm("v_fma_mix_f32 %0, %1, %2, %0 op_sel:[1,0,0] op_sel_hi:[1,0,0]" : "+v"(acc) : "v"(pk), "s"(hs))

#define MV_PAIR(wIc, wFc, wGc, wOc, k0) {                 \
    const float h0  = rlf(hv, (k0));                      \
    const float h1v = rlf(hv, (k0) + 1);                  \
    FMA_LO(aI, wIc, h0);  FMA_HI(aI, wIc, h1v);           \
    FMA_LO(aF, wFc, h0);  FMA_HI(aF, wFc, h1v);           \
    FMA_LO(aG, wGc, h0);  FMA_HI(aG, wGc, h1v);           \
    FMA_LO(aO, wOc, h0);  FMA_HI(aO, wOc, h1v); }

// one [204x51] matvec from LDS fp16 (rows padded to 56 halves, cols 51..55 zero)
template<int MOFF>
__device__ __forceinline__ void matvec_lds(const char* pb, float hv,
                                           float& aI, float& aF, float& aG, float& aO)
{
#pragma unroll
    for (int q = 0; q < 7; ++q) {
        const uint4 wI = *(const uint4*)(pb + (MOFF + 0 * GOFF) + q * 16);
        const uint4 wF = *(const uint4*)(pb + (MOFF + 1 * GOFF) + q * 16);
        const uint4 wG = *(const uint4*)(pb + (MOFF + 2 * GOFF) + q * 16);
        const uint4 wO = *(const uint4*)(pb + (MOFF + 3 * GOFF) + q * 16);
        MV_PAIR(wI.x, wF.x, wG.x, wO.x, 8 * q + 0);
        MV_PAIR(wI.y, wF.y, wG.y, wO.y, 8 * q + 2);
        MV_PAIR(wI.z, wF.z, wG.z, wO.z, 8 * q + 4);
        MV_PAIR(wI.w, wF.w, wG.w, wO.w, 8 * q + 6);
    }
}

// [204x51] matvec from packed-fp16 register weights: W[4*p+g] = (w[2p+1]<<16)|w[2p]
__device__ __forceinline__ void matvec_reg(const u32 (&W)[104], float hv,
                                           float& aI, float& aF, float& aG, float& aO)
{
#pragma unroll
    for (int p = 0; p < 26; ++p) {
        const float h0 = rlf(hv, 2 * p);
        FMA_LO(aI, W[4 * p + 0], h0);
        FMA_LO(aF, W[4 * p + 1], h0);
        FMA_LO(aG, W[4 * p + 2], h0);
        FMA_LO(aO, W[4 * p + 3], h0);
        if (2 * p + 1 < HH) {   // p==25 hi half is zero pad, skip
            const float h1v = rlf(hv, 2 * p + 1);
            FMA_HI(aI, W[4 * p + 0], h1v);
            FMA_HI(aF, W[4 * p + 1], h1v);
            FMA_HI(aG, W[4 * p + 2], h1v);
            FMA_HI(aO, W[4 * p + 3], h1v);
        }
    }
}

__global__ void __launch_bounds__(256, 1)
lstm2_kernel(const float* __restrict__ input,
             const float* __restrict__ w_ih1, const float* __restrict__ w_hh1,
             const float* __restrict__ b_ih1, const float* __restrict__ b_hh1,
             const float* __restrict__ w_ih2, const float* __restrict__ w_hh2,
             const float* __restrict__ b_ih2, const float* __restrict__ b_hh2,
             const float* __restrict__ w_lin, const float* __restrict__ b_lin,
             float* __restrict__ out, int T)
{
    __shared__ __align__(16) unsigned short sW[2 * G4 * RP];   // 58752 B: [w_ih2 | w_hh2] fp16

    const int tid  = threadIdx.x;
    const int lane = tid & 63;
    const int wid  = tid >> 6;
    const int row  = blockIdx.x * 4 + wid;          // one batch row per wave

    // ---- stage w_ih2 (m=0) and w_hh2 (m=1) into LDS as fp16 ----
    for (int idx = tid; idx < 2 * G4 * 56; idx += 256) {
        const int m  = idx / (G4 * 56);
        const int rc = idx - m * (G4 * 56);
        const int r  = rc / 56;
        const int c  = rc - r * 56;
        const float* src = m ? w_hh2 : w_ih2;
        const float v = (c < HH) ? src[r * HH + c] : 0.0f;
        sW[(m * G4 + r) * RP + c] = __half_as_ushort(__float2half(v));
    }
    __syncthreads();

    const int j = (lane < HH) ? lane : 0;           // inactive lanes mirror unit 0 (in-bounds)

    // ---- per-lane scalars ----
    const float wxI = w_ih1[j],          wxF = w_ih1[HH + j],
                wxG = w_ih1[2 * HH + j], wxO = w_ih1[3 * HH + j];
    const float bI1 = b_ih1[j]          + b_hh1[j];
    const float bF1 = b_ih1[HH + j]     + b_hh1[HH + j];
    const float bG1 = b_ih1[2 * HH + j] + b_hh1[2 * HH + j];
    const float bO1 = b_ih1[3 * HH + j] + b_hh1[3 * HH + j];
    const float bI2 = b_ih2[j]          + b_hh2[j];
    const float bF2 = b_ih2[HH + j]     + b_hh2[HH + j];
    const float bG2 = b_ih2[2 * HH + j] + b_hh2[2 * HH + j];
    const float bO2 = b_ih2[3 * HH + j] + b_hh2[3 * HH + j];
    const float wl  = w_lin[j];
    const float bl  = b_lin[0];

    // ---- w_hh1 packed fp16 in registers: 104 VGPRs ----
    u32 Wh1P[104];
#pragma unroll
    for (int p = 0; p < 26; ++p) {
#pragma unroll
        for (int g = 0; g < 4; ++g) {
            const float lo = w_hh1[(g * HH + j) * HH + 2 * p];
            const float hi = (2 * p + 1 < HH) ? w_hh1[(g * HH + j) * HH + 2 * p + 1] : 0.0f;
            Wh1P[4 * p + g] = (u32)__half_as_ushort(__float2half(lo))
                            | ((u32)__half_as_ushort(__float2half(hi)) << 16);
        }
    }

    const char* pb = (const char*)sW + j * RPB;     // this lane's unit-row base (j clamped: in-bounds)

    float h1 = 0.0f, c1 = 0.0f, h2 = 0.0f, c2 = 0.0f;
    const float* xrow = input + (size_t)row * T;
    float*       orow = out   + (size_t)row * T;

    for (int t0 = 0; t0 < T; t0 += 64) {
        const float xv = xrow[t0 + lane];           // coalesced prefetch of 64 x values

        for (int tt = 0; tt < 64; ++tt) {
            // -------- Phase A: layer-2 hh-part with OLD h2 (LDS fp16) --------
            float aI2 = bI2, aF2 = bF2, aG2 = bG2, aO2 = bO2;
            matvec_lds<MOFF1>(pb, h2, aI2, aF2, aG2, aO2);

            // -------- Phase B: layer 1 (x scalar + register fp16 w_hh1) --------
            const float x = rlf(xv, tt);            // tt uniform -> SGPR lane select
            float aI1 = fmaf(wxI, x, bI1);
            float aF1 = fmaf(wxF, x, bF1);
            float aG1 = fmaf(wxG, x, bG1);
            float aO1 = fmaf(wxO, x, bO1);
            matvec_reg(Wh1P, h1, aI1, aF1, aG1, aO1);
            c1 = fmaf(sigm(aF1), c1, sigm(aI1) * tanh_fast(aG1));
            h1 = sigm(aO1) * tanh_fast(c1);

            // -------- Phase C: layer-2 ih-part with NEW h1 (LDS fp16) --------
            matvec_lds<0>(pb, h1, aI2, aF2, aG2, aO2);
            c2 = fmaf(sigm(aF2), c2, sigm(aI2) * tanh_fast(aG2));
            h2 = sigm(aO2) * tanh_fast(c2);

            // -------- Phase D: y = <h2, w_lin> + b_lin  (DPP row-reduce, VALU-only) --------
            float yp = (lane < HH) ? h2 * wl : 0.0f;
            yp += __int_as_float(__builtin_amdgcn_update_dpp(0, __float_as_int(yp), 0x111, 0xF, 0xF, true));
            yp += __int_as_float(__builtin_amdgcn_update_dpp(0, __float_as_int(yp), 0x112, 0xF, 0xF, true));
            yp += __int_as_float(__builtin_amdgcn_update_dpp(0, __float_as_int(yp), 0x114, 0xF, 0xF, true));
            yp += __int_as_float(__builtin_amdgcn_update_dpp(0, __float_as_int(yp), 0x118, 0xF, 0xF, true));
            const float y = rlf(yp, 15) + rlf(yp, 31) + rlf(yp, 47) + rlf(yp, 63) + bl;
            if (lane == 0) orow[t0 + tt] = y;
        }
    }
}

extern "C" void kernel_launch(void* const* d_in, const int* in_sizes, int n_in,
                              void* d_out, int out_size, void* d_ws, size_t ws_size,
                              hipStream_t stream) {
    const float* input = (const float*)d_in[0];
    // d_in[1] = future (0) -- ignored
    const float* w_ih1 = (const float*)d_in[2];
    const float* w_hh1 = (const float*)d_in[3];
    const float* b_ih1 = (const float*)d_in[4];
    const float* b_hh1 = (const float*)d_in[5];
    const float* w_ih2 = (const float*)d_in[6];
    const float* w_hh2 = (const float*)d_in[7];
    const float* b_ih2 = (const float*)d_in[8];
    const float* b_hh2 = (const float*)d_in[9];
    const float* w_lin = (const float*)d_in[10];
    const float* b_lin = (const float*)d_in[11];
    float* out = (float*)d_out;

    const int T = 1024;
    const int B = in_sizes[0] / T;                  // 1024

    lstm2_kernel<<<B / 4, 256, 0, stream>>>(input,
                                            w_ih1, w_hh1, b_ih1, b_hh1,
                                            w_ih2, w_hh2, b_ih2, b_hh2,
                                            w_lin, b_lin, out, T);
}